// Round 13
// baseline (16767.113 us; speedup 1.0000x reference)
//
#include <hip/hip_runtime.h>
#include <stdint.h>

typedef _Float16 f16;
typedef _Float16 half8 __attribute__((ext_vector_type(8)));
typedef float f32x4 __attribute__((ext_vector_type(4)));
typedef unsigned long long u64;

#define T_SEQ 1024
#define NWG 136            // 64 L0 + 64 L1 + 8 e-producers
#define FS 8               // flag stride in u32 -> 32B
#define DE 3               // e ring depth
#define HPLANE 16384       // f16 per h plane (32 KB)
#define ESLOT 24576        // f16 per e slot (48 KB)

// ws layout (memset [0,8192) each launch)
#define OFF_FA 0                     // fA[64]: L0 progress
#define OFF_FB 2048                  // fB[64]: L1 progress
#define OFF_FP 4096                  // fP[8]:  producer progress
#define WS_H0 8192                   // 4 planes x 32768 B
#define WS_H1 (WS_H0 + 131072)       // 2 planes x 32768 B
#define WS_E  (WS_H1 + 65536)        // 3 slots x 49152 B -> end 352256

static __device__ __forceinline__ u64 ld64(const u64* p) {
    return __hip_atomic_load(p, __ATOMIC_RELAXED, __HIP_MEMORY_SCOPE_AGENT);
}
static __device__ __forceinline__ void st64(u64* p, u64 v) {
    __hip_atomic_store(p, v, __ATOMIC_RELAXED, __HIP_MEMORY_SCOPE_AGENT);
}
static __device__ __forceinline__ uint32_t ld32(const uint32_t* p) {
    return __hip_atomic_load(p, __ATOMIC_RELAXED, __HIP_MEMORY_SCOPE_AGENT);
}
static __device__ __forceinline__ void st32(uint32_t* p, uint32_t v) {
    __hip_atomic_store(p, v, __ATOMIC_RELAXED, __HIP_MEMORY_SCOPE_AGENT);
}
static __device__ __forceinline__ half8 h8(u64 lo, u64 hi) {
    union { u64 q[2]; half8 v; } u; u.q[0] = lo; u.q[1] = hi; return u.v;
}
static __device__ __forceinline__ half8 ld_h8(const f16* p) {
    u64 lo = ld64((const u64*)p);
    u64 hi = ld64((const u64*)p + 1);
    return h8(lo, hi);
}
// wave-parallel single poll over fA/fB/(fP)
static __device__ __forceinline__ void pollM(const uint32_t* fA, uint32_t needA,
                                             const uint32_t* fB, uint32_t needB,
                                             const uint32_t* fP, uint32_t needP,
                                             int lane) {
    const uint32_t* pa = fA + (size_t)lane * FS;
    const uint32_t* pb = fB + (size_t)lane * FS;
    const uint32_t* pp = fP + (size_t)(lane & 7) * FS;
    while (true) {
        uint32_t va = ld32(pa);
        uint32_t vb = ld32(pb);
        uint32_t vp = ld32(pp);
        if (__all((va >= needA) && (vb >= needB) && (vp >= needP))) break;
        __builtin_amdgcn_s_sleep(1);
    }
    __builtin_amdgcn_sched_barrier(0);
}
// simple poll (producers)
static __device__ __forceinline__ void pollA(const uint32_t* flags, int n,
                                             uint32_t need, int lane) {
    const uint32_t* p = flags + (size_t)(lane < n ? lane : 0) * FS;
    while (true) {
        uint32_t v = ld32(p);
        if (__all(v >= need)) break;
        __builtin_amdgcn_s_sleep(1);
    }
    __builtin_amdgcn_sched_barrier(0);
}

__global__ void __launch_bounds__(256, 1)
lstm_fused(const int* __restrict__ x, const float* __restrict__ emb,
           const float* __restrict__ w_ih0, const float* __restrict__ w_hh0,
           const float* __restrict__ b_ih0, const float* __restrict__ b_hh0,
           const float* __restrict__ w_ih1, const float* __restrict__ w_hh1,
           const float* __restrict__ b_ih1, const float* __restrict__ b_hh1,
           const float* __restrict__ fc_w, const float* __restrict__ fc_b,
           float* __restrict__ out, uint8_t* __restrict__ ws)
{
    const int wg   = blockIdx.x;
    const int tid  = threadIdx.x;
    const int lane = tid & 63;
    const int wave = tid >> 6;
    const int mtile = wave >> 1;       // batch half
    const int ntile = wave & 1;        // gate-col half
    const int r8   = lane & 15;
    const int kgb  = lane >> 4;
    const int tb = tid >> 3, tj = tid & 7;

    uint32_t* fA = (uint32_t*)(ws + OFF_FA);
    uint32_t* fB = (uint32_t*)(ws + OFF_FB);
    uint32_t* fP = (uint32_t*)(ws + OFF_FP);
    f16* h0buf = (f16*)(ws + WS_H0);
    f16* h1buf = (f16*)(ws + WS_H1);
    f16* ering = (f16*)(ws + WS_E);

    // ================= e-producer wgs (128..135) =================
    if (wg >= 128) {
        const int p = wg - 128;        // batch rows 4p..4p+3
        auto gather = [&](int t, int slot) {
#pragma unroll
            for (int rr = 0; rr < 2; ++rr) {
                int idx2 = rr * 256 + tid;
                if (idx2 < 384) {
                    int bl = idx2 / 96, seg = idx2 % 96, k0 = seg * 8;
                    int b = p * 4 + bl;
                    int tok = x[b * T_SEQ + t];
                    const float* src = emb + (size_t)tok * 768 + k0;
                    float4 v0 = ((const float4*)src)[0];
                    float4 v1 = ((const float4*)src)[1];
                    union { half8 h; u64 q[2]; } u;
                    u.h[0] = (f16)v0.x; u.h[1] = (f16)v0.y; u.h[2] = (f16)v0.z; u.h[3] = (f16)v0.w;
                    u.h[4] = (f16)v1.x; u.h[5] = (f16)v1.y; u.h[6] = (f16)v1.z; u.h[7] = (f16)v1.w;
                    u64* dst = (u64*)(ering + (size_t)slot * ESLOT + ((size_t)seg * 32 + b) * 8);
                    st64(dst, u.q[0]); st64(dst + 1, u.q[1]);
                }
            }
        };
        gather(0, 0); gather(1, 1); gather(2, 2);
        asm volatile("s_waitcnt vmcnt(0)" ::: "memory");
        __syncthreads();
        if (tid == 0) st32(fP + p * FS, 3u);
        for (int g = 3; g < T_SEQ; ++g) {
            pollA(fA, 64, (uint32_t)(g - 1), lane);   // L0 done e_{g-3} (slot g%3 free)
            gather(g, g % DE);
            asm volatile("s_waitcnt vmcnt(0)" ::: "memory");
            __syncthreads();
            if (tid == 0) st32(fP + p * FS, (uint32_t)(g + 1));
        }
        return;
    }

    // ================= recurrence wgs =================
    const bool isL0 = (wg < 64);
    const int wloc  = isL0 ? wg : wg - 64;
    const int j0    = wloc * 8;

    __shared__ half8 astage[80 * 64];   // 80 KB A-fragment staging
    __shared__ float accs[32][33];
    __shared__ float bias_lds[32];
    __shared__ f16   hsh[32][8];

    // ---- weights (compiler-managed; remat from L2 measured-cheap) ----
    const int nrow = ((ntile * 2 + (r8 >> 3)) << 9) + j0 + (r8 & 7);
    half8 breg[40];
    if (isL0) {
#pragma unroll
        for (int kc = 0; kc < 40; ++kc) {
            int k = kc * 32 + kgb * 8;
            const float* src = (k < 768) ? (w_ih0 + (size_t)nrow * 768 + k)
                                         : (w_hh0 + (size_t)nrow * 512 + (k - 768));
            half8 v;
#pragma unroll
            for (int e = 0; e < 8; ++e) v[e] = (f16)src[e];
            breg[kc] = v;
        }
    } else {
#pragma unroll
        for (int kc = 0; kc < 32; ++kc) {
            int k = kc * 32 + kgb * 8;
            const float* src = (k < 512) ? (w_ih1 + (size_t)nrow * 512 + k)
                                         : (w_hh1 + (size_t)nrow * 512 + (k - 512));
            half8 v;
#pragma unroll
            for (int e = 0; e < 8; ++e) v[e] = (f16)src[e];
            breg[kc] = v;
        }
    }
    if (tid < 32) {
        int n2 = ((tid >> 3) << 9) + j0 + (tid & 7);
        bias_lds[tid] = isL0 ? (b_ih0[n2] + b_hh0[n2]) : (b_ih1[n2] + b_hh1[n2]);
    }

    // ---- zero-init h0 plane 3 (h0_{-1}) and h1 plane 1 (h1_{-1}) ----
    {
        int gid = wg * 256 + tid;      // wgs 0..31 cover 8192 u64
        if (gid < 8192) {
            u64* base = (gid < 4096) ? (u64*)(h0buf + 3 * HPLANE)
                                     : (u64*)(h1buf + 1 * HPLANE);
            st64(base + (gid & 4095), 0ULL);
        }
    }
    asm volatile("s_waitcnt vmcnt(0)" ::: "memory");
    __syncthreads();
    if (tid == 0) st32((isL0 ? fA : fB) + wloc * FS, isL0 ? 1u : 2u);

    float cst = 0.f;
    const int crow0 = mtile * 16 + (lane >> 4) * 4;   // C/D: row=(lane>>4)*4+q
    const int ccol  = ntile * 16 + r8;                //      col=lane&15

    const int sBeg = isL0 ? 0 : 1;
    const int sEnd = isL0 ? T_SEQ : T_SEQ + 1;
    const int NKC  = isL0 ? 40 : 32;   // kc per mtile
    const int NST  = isL0 ? 20 : 16;   // staged frags per wave

    for (int s = sBeg; s < sEnd; ++s) {
        // ---- ONE merged poll ----
        if (isL0) pollM(fA, (uint32_t)(s + 1), fB, (uint32_t)(s > 0 ? s - 1 : 0),
                        fP, (uint32_t)(s + 1), lane);
        else      pollM(fA, (uint32_t)(s + 1), fB, (uint32_t)(s + 1),
                        fP, 0u, lane);
        // ---- cooperative A staging: each unique fragment loaded ONCE ----
        const f16* pe = ering + (size_t)(s % DE) * ESLOT;                 // e_s (L0)
        const f16* ph0 = h0buf + (size_t)((s + 3) & 3) * HPLANE;          // h0_{s-1}
        const f16* ph1 = h1buf + (size_t)(s & 1) * HPLANE;                // h1_{s-2} (L1)
        {
            half8 stg[20];
#pragma unroll
            for (int j = 0; j < 20; ++j) {
                if (j >= NST) break;
                int f = wave * NST + j;
                int mt = f / NKC, kc = f % NKC;
                const f16* base; int kk;
                if (isL0) { base = (kc < 24) ? pe : ph0; kk = (kc < 24) ? kc : kc - 24; }
                else      { base = (kc < 16) ? ph0 : ph1; kk = (kc < 16) ? kc : kc - 16; }
                stg[j] = ld_h8(base + (((size_t)(kk * 4 + kgb) * 32 + mt * 16 + r8) << 3));
            }
#pragma unroll
            for (int j = 0; j < 20; ++j) {
                if (j >= NST) break;
                astage[(size_t)(wave * NST + j) * 64 + lane] = stg[j];
            }
        }
        __syncthreads();
        // ---- MFMA from LDS ----
        f32x4 acc0 = {0.f, 0.f, 0.f, 0.f}, acc1 = {0.f, 0.f, 0.f, 0.f};
#pragma unroll
        for (int kc = 0; kc < 40; ++kc) {
            if (kc >= NKC) break;
            half8 a = astage[(size_t)(mtile * NKC + kc) * 64 + lane];
            if (kc & 1) acc1 = __builtin_amdgcn_mfma_f32_16x16x32_f16(a, breg[kc], acc1, 0, 0, 0);
            else        acc0 = __builtin_amdgcn_mfma_f32_16x16x32_f16(a, breg[kc], acc0, 0, 0, 0);
        }
        {
            f32x4 accv = acc0 + acc1;
#pragma unroll
            for (int q = 0; q < 4; ++q) accs[crow0 + q][ccol] = accv[q];
        }
        __syncthreads();
        {
            float gi = accs[tb][tj]      + bias_lds[tj];
            float gf = accs[tb][8 + tj]  + bias_lds[8 + tj];
            float gg = accs[tb][16 + tj] + bias_lds[16 + tj];
            float go = accs[tb][24 + tj] + bias_lds[24 + tj];
            float si = __builtin_amdgcn_rcpf(1.f + __expf(-gi));
            float sf = __builtin_amdgcn_rcpf(1.f + __expf(-gf));
            float so = __builtin_amdgcn_rcpf(1.f + __expf(-go));
            float tg = 1.f - 2.f * __builtin_amdgcn_rcpf(__expf(2.f * gg) + 1.f);
            cst = sf * cst + si * tg;
            float hv = so * (1.f - 2.f * __builtin_amdgcn_rcpf(__expf(2.f * cst) + 1.f));
            hsh[tb][tj] = (f16)hv;
        }
        __syncthreads();
        if (tid < 32) {                 // publish own 8-col slice (wave 0)
            f16* plane = isL0 ? (h0buf + (size_t)(s & 3) * HPLANE)         // h0_s
                              : (h1buf + (size_t)((s + 1) & 1) * HPLANE);  // h1_{s-1}
            u64* dst = (u64*)plane + ((size_t)wloc * 32 + tid) * 2;
            const u64* srcp = (const u64*)hsh + tid * 2;
            u64 q0 = srcp[0], q1 = srcp[1];
            st64(dst, q0); st64(dst + 1, q1);
        }
        if (tid == 0) {
            asm volatile("s_waitcnt vmcnt(0)" ::: "memory");
            st32((isL0 ? fA : fB) + wloc * FS, (uint32_t)(s + 2));
        }
    }

    // ---------- FC epilogue (wg 0): h2 = h1_{1023} = plane 1 ----------
    if (wg == 0) {
        pollA(fB, 64, (uint32_t)(T_SEQ + 2), lane);
        const u64* h2g = (const u64*)(h1buf + 1 * HPLANE);
        u64* stg = (u64*)astage;       // reuse staging LDS
        for (int i = tid; i < 4096; i += 256)
            stg[i] = ld64(h2g + i);
        __syncthreads();
        if (tid < 160) {
            int b = tid / 5, n = tid % 5;
            const f16* h2 = (const f16*)stg;
            float fsum = fc_b[n];
#pragma unroll 8
            for (int j = 0; j < 512; ++j)
                fsum += (float)h2[((j >> 3) * 32 + b) * 8 + (j & 7)] * fc_w[n * 512 + j];
            out[b * 5 + n] = fsum;
        }
    }
}

extern "C" void kernel_launch(void* const* d_in, const int* in_sizes, int n_in,
                              void* d_out, int out_size, void* d_ws, size_t ws_size,
                              hipStream_t stream) {
    (void)in_sizes; (void)n_in; (void)out_size; (void)ws_size;
    hipMemsetAsync(d_ws, 0, 8192, stream);   // flags start at 0
    lstm_fused<<<dim3(NWG), dim3(256), 0, stream>>>(
        (const int*)d_in[0],  (const float*)d_in[1],
        (const float*)d_in[2], (const float*)d_in[3],
        (const float*)d_in[4], (const float*)d_in[5],
        (const float*)d_in[6], (const float*)d_in[7],
        (const float*)d_in[8], (const float*)d_in[9],
        (const float*)d_in[10], (const float*)d_in[11],
        (float*)d_out, (uint8_t*)d_ws);
}